// Round 11
// baseline (56.779 us; speedup 1.0000x reference)
//
#include <hip/hip_runtime.h>
#include <hip/hip_bf16.h>
#include <math.h>

// image: (B=32, D=64, H=64, W=128) f32
// polar_log_depths: (B=32, H=64, W=128, S=64) f32
// outputs: image_polar (B,D,Z=64,W) f32, cell_score (B,W,Z) f32, concat flat.
#define B_ 32
#define D_ 64
#define H_ 64
#define W_ 128
#define S_ 64
#define Z_ 64

typedef __attribute__((ext_vector_type(8))) short bf16x8;
typedef __attribute__((ext_vector_type(4))) float f32x4;

static __device__ __forceinline__ short f2bf(float f) {
    union { __hip_bfloat16 h; short s; } u;
    u.h = __float2bfloat16(f);
    return u.s;
}
static __device__ __forceinline__ float getc(const float4& v, int k) {
    switch (k) { case 0: return v.x; case 1: return v.y; case 2: return v.z; default: return v.w; }
}

// Swizzled byte offset of a 16B column-octet slot in an 8KB [64 rows][128 B] plane.
static __device__ __forceinline__ int swz(int w, int row, int oct) {
    return w * 8192 + row * 128 + (((oct ^ row ^ w) & 7) << 4);
}

// ============================ Kernel A ====================================
// Per (b, w-quad): polar -> scores (MFMA w/ register Wz) -> softmax ->
// normalized P^T bf16 -> stash (coalesced 64-B chunks inside the owning
// B-block's future out_img region) + cell_score.
// Stash layout: logical P^T linear byte L = w_slot*8192 + z*128 + h*2 maps to
// chunk c = L>>6 stored at out_img f32 offset
//   ((b*64 + (c>>6))*64 + (c&63))*128 + oct_id*16 + (L&63)/4
// i.e. d-rows 0..32 of the block's exclusive 16 w-columns.
__global__ __launch_bounds__(1024, 8)
void polar_prob_kernel(const float* __restrict__ polar,
                       float* __restrict__ out_img,
                       float* __restrict__ out_cell) {
    __shared__ __align__(16) unsigned char sP[4 * 8192];

    const int t = threadIdx.x;
    const int cpx = gridDim.x >> 3;                   // 128
    const int logical = (blockIdx.x & 7) * cpx + (blockIdx.x >> 3);
    const int b   = logical >> 5;
    const int wt4 = logical & 31;
    const int w0  = wt4 << 2;

    // ---- polar loads: 4 lanes x 16B contiguous per 256B row (64B granules) ----
    const int q4 = t & 3;
    const int rr = t >> 2;                            // w*64 + h
    const int w_p = rr >> 6, h_p = rr & 63;
    const float* src = polar + ((size_t)((b * H_ + h_p) * W_ + w0 + w_p)) * S_ + q4 * 16;
    float4 pr[4];
#pragma unroll
    for (int k = 0; k < 4; ++k)
        pr[k] = *(const float4*)(src + k * 4);
#pragma unroll
    for (int c = 0; c < 2; ++c) {
        bf16x8 v;
#pragma unroll
        for (int e = 0; e < 8; ++e)
            v[e] = f2bf(getc(pr[c * 2 + (e >> 2)], e & 3));
        *(bf16x8*)(sP + swz(w_p, h_p, q4 * 2 + c)) = v;
    }
    __syncthreads();

    // ---- S-MFMA with register-built Wz; wave = (wS, zq) ----
    const int lane = t & 63;
    const int wv   = t >> 6;
    const int fr   = lane & 15, lg = lane >> 4;
    const int wS   = wv >> 2, zq = wv & 3;
    const int z    = zq * 16 + fr;
    const float posf = (log2f(0.5f + 0.5f * (float)z) + 1.0f) * 10.5f;  // (63/6)
    int i0 = (int)floorf(posf);
    i0 = i0 < 0 ? 0 : (i0 > S_ - 1 ? S_ - 1 : i0);
    const int i1 = (i0 + 1 > S_ - 1) ? (S_ - 1) : (i0 + 1);
    const float wz = posf - (float)i0;

    bf16x8 bw[2];
#pragma unroll
    for (int ks = 0; ks < 2; ++ks)
#pragma unroll
        for (int e = 0; e < 8; ++e) {
            const int s = ks * 32 + lg * 8 + e;
            const float v = (s == i0 ? 1.0f - wz : 0.0f) + (s == i1 ? wz : 0.0f);
            bw[ks][e] = f2bf(v);
        }

    f32x4 sacc[4] = {};
#pragma unroll
    for (int ks = 0; ks < 2; ++ks)
#pragma unroll
        for (int mt = 0; mt < 4; ++mt) {
            const bf16x8 a = *(const bf16x8*)(sP + swz(wS, mt * 16 + fr, ks * 4 + lg));
            sacc[mt] = __builtin_amdgcn_mfma_f32_16x16x32_bf16(a, bw[ks], sacc[mt], 0, 0, 0);
        }

    // ---- softmax over h, no max-subtract (|score| <~ 6; verified R8/R10) ----
    float ex[4][4];
    float ss = 0.0f;
#pragma unroll
    for (int mt = 0; mt < 4; ++mt)
#pragma unroll
        for (int r = 0; r < 4; ++r) {
            const float e = __expf(sacc[mt][r]);
            ex[mt][r] = e;
            ss += e;
        }
    ss += __shfl_xor(ss, 16);
    ss += __shfl_xor(ss, 32);
    if (lg == 0)
        out_cell[((size_t)b * W_ + w0 + wS) * Z_ + z] = __logf(ss);
    const float inv = 1.0f / ss;
    __syncthreads();   // all S reads of sP done; safe to overwrite

    // ---- normalized P^T -> sP rows z (b64 packs of 4 h-contiguous bf16) ----
#pragma unroll
    for (int mt = 0; mt < 4; ++mt) {
        const short p0 = f2bf(ex[mt][0] * inv);
        const short p1 = f2bf(ex[mt][1] * inv);
        const short p2 = f2bf(ex[mt][2] * inv);
        const short p3 = f2bf(ex[mt][3] * inv);
        int2 pk;
        pk.x = (p0 & 0xffff) | (p1 << 16);
        pk.y = (p2 & 0xffff) | (p3 << 16);
        *(int2*)(sP + swz(wS, z, mt * 2 + (lg >> 1)) + ((lg & 1) << 3)) = pk;
    }
    __syncthreads();

    // ---- stream P^T to stash (64-B granule stores) ----
    const int octid = wt4 >> 2;
    const int wsub  = (wt4 & 3) << 2;
    const int w0B   = octid << 4;
#pragma unroll
    for (int p = 0; p < 2; ++p) {
        const int u  = t + p * 1024;
        const int wl = u >> 9, zz = (u >> 3) & 63, oc = u & 7;
        const float4 v = *(const float4*)(sP + swz(wl, zz, oc));
        const int ws = wsub + wl;
        float* dst = out_img
            + ((size_t)((b * 64 + ws * 2 + (zz >> 5)) * 64 + ((zz & 31) * 2 + (oc >> 2)))) * 128
            + w0B + ((oc & 3) << 2);
        *(float4*)dst = v;
    }
}

// ============================ Kernel B ====================================
// Per (b, w-oct of 16): stage image bf16 [w][d][h] (64-B coalesced loads),
// PV-MFMA with P^T fragments streamed from the stash, wave-local regroup,
// 64-B granule stores. Overwrites the stash region (after all reads).
__global__ __launch_bounds__(1024, 4)
void polar_pv_kernel(const float* __restrict__ image,
                     const float* stash,
                     float* out_img) {
    __shared__ __align__(16) unsigned char sA[16 * 8192];   // 128 KB; tail reused for regroup

    const int t = threadIdx.x;
    const int cpx = gridDim.x >> 3;                   // 32
    const int logical = (blockIdx.x & 7) * cpx + (blockIdx.x >> 3);
    const int b   = logical >> 3;
    const int oct = logical & 7;
    const int w0B = oct << 4;

    // ---- stage image: quad = (d, h-quad) unit of 4 rows x 16 w ----
    const int wq = t & 3;
#pragma unroll
    for (int p = 0; p < 4; ++p) {
        const int unit = p * 256 + (t >> 2);          // 0..1023 = d*16 + hq
        const int d = unit >> 4, hq = unit & 15;
        float4 v[4];
#pragma unroll
        for (int k = 0; k < 4; ++k)
            v[k] = *(const float4*)(image + ((size_t)((b * D_ + d) * H_ + hq * 4 + k)) * W_ + w0B + wq * 4);
#pragma unroll
        for (int c = 0; c < 4; ++c) {
            const int wl = wq * 4 + c;                // this lane's w-local of component c
            int2 pk;
            pk.x = (f2bf(getc(v[0], c)) & 0xffff) | (f2bf(getc(v[1], c)) << 16);
            pk.y = (f2bf(getc(v[2], c)) & 0xffff) | (f2bf(getc(v[3], c)) << 16);
            *(int2*)(sA + swz(wl, d, hq >> 1) + ((hq & 1) << 3)) = pk;
        }
    }
    __syncthreads();

    // ---- PV GEMM: wave (dt, zt) does 16d x 16z x all 16 w, K=64 ----
    const int lane = t & 63;
    const int wv   = t >> 6;
    const int fr   = lane & 15, lg = lane >> 4;
    const int dt   = wv >> 2, zt = wv & 3;
    const int z    = zt * 16 + fr;
    const int rowA = dt * 16 + fr;
    // stash address of P^T fragment (w, ks): base + w*16384 + ks*128 (f32 units)
    const float* pbase = stash
        + ((size_t)((b * 64 + (z >> 5)) * 64 + (z & 31) * 2)) * 128
        + w0B + (lg << 2);

    f32x4 acc[16] = {};
#pragma unroll
    for (int w = 0; w < 16; ++w)
#pragma unroll
        for (int ks = 0; ks < 2; ++ks) {
            const bf16x8 a  = *(const bf16x8*)(sA + swz(w, rowA, ks * 4 + lg));
            const bf16x8 bb = *(const bf16x8*)(pbase + w * 16384 + ks * 128);
            acc[w] = __builtin_amdgcn_mfma_f32_16x16x32_bf16(a, bb, acc[w], 0, 0, 0);
        }
    __syncthreads();   // all sA reads done; reuse for regroup

    // ---- wave-local regroup (80-B pitch -> even bank classes), 64-B stores ----
    unsigned char* rg = sA + wv * 5120;
    const int dzw = lg * 16 + fr;                     // writer's (d-sub, z-sub)
#pragma unroll
    for (int r = 0; r < 4; ++r) {
#pragma unroll
        for (int j = 0; j < 4; ++j) {                 // w-quad j (static acc indices)
            float4 v;
            v.x = acc[j * 4 + 0][r];
            v.y = acc[j * 4 + 1][r];
            v.z = acc[j * 4 + 2][r];
            v.w = acc[j * 4 + 3][r];
            *(float4*)(rg + dzw * 80 + j * 16) = v;
        }
#pragma unroll
        for (int i = 0; i < 4; ++i) {
            const int dzr = i * 16 + (lane >> 2);
            const float4 o = *(const float4*)(rg + dzr * 80 + (lane & 3) * 16);
            const int d  = dt * 16 + i * 4 + r;
            const int zz = zt * 16 + (lane >> 2);
            *(float4*)(out_img + ((size_t)((b * D_ + d) * Z_ + zz)) * W_ + w0B + (lane & 3) * 4) = o;
        }
    }
}

extern "C" void kernel_launch(void* const* d_in, const int* in_sizes, int n_in,
                              void* d_out, int out_size, void* d_ws, size_t ws_size,
                              hipStream_t stream) {
    const float* image = (const float*)d_in[0];
    const float* polar = (const float*)d_in[1];
    float* out_img  = (float*)d_out;
    float* out_cell = out_img + (size_t)B_ * D_ * Z_ * W_;
    (void)d_ws; (void)ws_size;
    polar_prob_kernel<<<dim3(1024), 1024, 0, stream>>>(polar, out_img, out_cell);
    polar_pv_kernel<<<dim3(256), 1024, 0, stream>>>(image, out_img, out_img);
}